// Round 1
// baseline (172.900 us; speedup 1.0000x reference)
//
#include <hip/hip_runtime.h>
#include <stdint.h>

#define KK 1000
#define NN 1000
#define MM 900000
#define FF 7
#define SENTINEL -9999.0f

// ---------------- init: zero the packed grid (ws is poisoned 0xAA) ----------
__global__ __launch_bounds__(256) void init_grid(ulonglong2* __restrict__ g, int n2) {
    int i = blockIdx.x * 256 + threadIdx.x;
    if (i < n2) g[i] = make_ulonglong2(0ULL, 0ULL);
}

// ---------------- MLP + last-write-wins scatter -----------------------------
__global__ __launch_bounds__(256) void mlp_scatter(
    const float* __restrict__ in,    // [F][M]
    const int*   __restrict__ idx,   // [2][M]
    const float* __restrict__ w1, const float* __restrict__ b1,   // 18x7, 18
    const float* __restrict__ w2, const float* __restrict__ b2,   // 36x18, 36
    const float* __restrict__ w3, const float* __restrict__ b3,   // 36x36, 36
    const float* __restrict__ w4, const float* __restrict__ b4,   // 1x36, 1
    unsigned long long* __restrict__ grid)                        // K*N packed
{
    int m = blockIdx.x * 256 + threadIdx.x;
    if (m >= MM) return;

    float x[FF];
#pragma unroll
    for (int f = 0; f < FF; ++f) x[f] = in[f * MM + m];

    float h1[18];
#pragma unroll
    for (int o = 0; o < 18; ++o) {
        float a = b1[o];
#pragma unroll
        for (int i = 0; i < FF; ++i) a = fmaf(w1[o * FF + i], x[i], a);
        h1[o] = fmaxf(a, 0.0f);
    }

    float h2[36];
#pragma unroll
    for (int o = 0; o < 36; ++o) {
        float a = b2[o];
#pragma unroll
        for (int i = 0; i < 18; ++i) a = fmaf(w2[o * 18 + i], h1[i], a);
        h2[o] = fmaxf(a, 0.0f);
    }

    float h3[36];
#pragma unroll
    for (int o = 0; o < 36; ++o) {
        float a = b3[o];
#pragma unroll
        for (int i = 0; i < 36; ++i) a = fmaf(w3[o * 36 + i], h2[i], a);
        h3[o] = fmaxf(a, 0.0f);
    }

    float v = b4[0];
#pragma unroll
    for (int i = 0; i < 36; ++i) v = fmaf(w4[i], h3[i], v);

    int r = idx[m];
    int c = idx[MM + m];
    // high word = m+1 (unique, later m wins => numpy last-write-wins),
    // low word = value bits (payload only, never decides the compare)
    unsigned long long packed =
        ((unsigned long long)(unsigned)(m + 1) << 32) | (unsigned)__float_as_uint(v);
    atomicMax(&grid[r * NN + c], packed);
}

// ---------------- row max: one block per row --------------------------------
__global__ __launch_bounds__(256) void row_max_k(const unsigned long long* __restrict__ g,
                                                 float* __restrict__ out) {
    int r = blockIdx.x;
    float mx = SENTINEL;
    for (int c = threadIdx.x; c < NN; c += 256) {
        unsigned long long p = g[(size_t)r * NN + c];
        if (p) mx = fmaxf(mx, __uint_as_float((unsigned)p));
    }
    __shared__ float red[256];
    red[threadIdx.x] = mx;
    __syncthreads();
    for (int s = 128; s > 0; s >>= 1) {
        if (threadIdx.x < s) red[threadIdx.x] = fmaxf(red[threadIdx.x], red[threadIdx.x + s]);
        __syncthreads();
    }
    if (threadIdx.x == 0) out[r] = red[0];
}

// ---------------- col max: partials over row-chunks, then final -------------
#define CCHUNKS 25
#define CROWS   (KK / CCHUNKS)   // 40

__global__ __launch_bounds__(256) void col_partial(const unsigned long long* __restrict__ g,
                                                   float* __restrict__ part) {
    int n = blockIdx.x * 256 + threadIdx.x;
    if (n >= NN) return;
    int k0 = blockIdx.y * CROWS;
    float mx = SENTINEL;
    for (int k = k0; k < k0 + CROWS; ++k) {
        unsigned long long p = g[(size_t)k * NN + n];
        if (p) mx = fmaxf(mx, __uint_as_float((unsigned)p));
    }
    part[blockIdx.y * NN + n] = mx;
}

__global__ __launch_bounds__(256) void col_final(const float* __restrict__ part,
                                                 float* __restrict__ out) {
    int n = blockIdx.x * 256 + threadIdx.x;
    if (n >= NN) return;
    float mx = SENTINEL;
#pragma unroll
    for (int c = 0; c < CCHUNKS; ++c) mx = fmaxf(mx, part[c * NN + n]);
    out[KK + n] = mx;
}

extern "C" void kernel_launch(void* const* d_in, const int* in_sizes, int n_in,
                              void* d_out, int out_size, void* d_ws, size_t ws_size,
                              hipStream_t stream) {
    const float* in  = (const float*)d_in[0];
    // d_in[1] = T_out (zeros) — unused
    const int*   idx = (const int*)d_in[2];
    const float* w1  = (const float*)d_in[3];
    const float* b1  = (const float*)d_in[4];
    const float* w2  = (const float*)d_in[5];
    const float* b2  = (const float*)d_in[6];
    const float* w3  = (const float*)d_in[7];
    const float* b3  = (const float*)d_in[8];
    const float* w4  = (const float*)d_in[9];
    const float* b4  = (const float*)d_in[10];

    unsigned long long* grid = (unsigned long long*)d_ws;            // 8 MB
    float* part = (float*)((char*)d_ws + (size_t)KK * NN * 8);       // 100 KB
    float* out  = (float*)d_out;

    const int n2 = (KK * NN) / 2;  // ulonglong2 elements
    init_grid<<<(n2 + 255) / 256, 256, 0, stream>>>((ulonglong2*)grid, n2);

    mlp_scatter<<<(MM + 255) / 256, 256, 0, stream>>>(
        in, idx, w1, b1, w2, b2, w3, b3, w4, b4, grid);

    row_max_k<<<KK, 256, 0, stream>>>(grid, out);
    col_partial<<<dim3(4, CCHUNKS), 256, 0, stream>>>(grid, part);
    col_final<<<4, 256, 0, stream>>>(part, out);
}

// Round 2
// 172.741 us; speedup vs baseline: 1.0009x; 1.0009x over previous
//
#include <hip/hip_runtime.h>
#include <stdint.h>

#define KK 1000
#define NN 1000
#define MM 900000
#define FF 7
#define SENTINEL -9999.0f

// ---------------- init: zero the packed grid (ws is poisoned 0xAA) ----------
__global__ __launch_bounds__(256) void init_grid(ulonglong2* __restrict__ g, int n2) {
    int i = blockIdx.x * 256 + threadIdx.x;
    if (i < n2) g[i] = make_ulonglong2(0ULL, 0ULL);
}

// ---------------- MLP + last-write-wins scatter -----------------------------
// __launch_bounds__(256, 4): cap VGPR at 128 so h1/h2 + temps stay in
// registers (R1: default budget gave VGPR=40 -> ~20MB scratch spill traffic,
// VALUBusy capped at 64%).
__global__ __launch_bounds__(256, 4) void mlp_scatter(
    const float* __restrict__ in,    // [F][M]
    const int*   __restrict__ idx,   // [2][M]
    const float* __restrict__ w1, const float* __restrict__ b1,   // 18x7, 18
    const float* __restrict__ w2, const float* __restrict__ b2,   // 36x18, 36
    const float* __restrict__ w3, const float* __restrict__ b3,   // 36x36, 36
    const float* __restrict__ w4, const float* __restrict__ b4,   // 1x36, 1
    unsigned long long* __restrict__ grid)                        // K*N packed
{
    int m = blockIdx.x * 256 + threadIdx.x;
    if (m >= MM) return;

    float x[FF];
#pragma unroll
    for (int f = 0; f < FF; ++f) x[f] = in[f * MM + m];

    float h1[18];
#pragma unroll
    for (int o = 0; o < 18; ++o) {
        float a = b1[o];
#pragma unroll
        for (int i = 0; i < FF; ++i) a = fmaf(w1[o * FF + i], x[i], a);
        h1[o] = fmaxf(a, 0.0f);
    }

    float h2[36];
#pragma unroll
    for (int o = 0; o < 36; ++o) {
        float a = b2[o];
#pragma unroll
        for (int i = 0; i < 18; ++i) a = fmaf(w2[o * 18 + i], h1[i], a);
        h2[o] = fmaxf(a, 0.0f);
    }

    // Layer 3 fused with layer 4: h3[o] never materializes as an array
    // (saves 36 live VGPRs -> peak live set ~h2[36]+temps).
    float v = b4[0];
#pragma unroll
    for (int o = 0; o < 36; ++o) {
        float a = b3[o];
#pragma unroll
        for (int i = 0; i < 36; ++i) a = fmaf(w3[o * 36 + i], h2[i], a);
        v = fmaf(w4[o], fmaxf(a, 0.0f), v);
    }

    int r = idx[m];
    int c = idx[MM + m];
    // high word = m+1 (unique, later m wins => numpy last-write-wins),
    // low word = value bits (payload only, never decides the compare)
    unsigned long long packed =
        ((unsigned long long)(unsigned)(m + 1) << 32) | (unsigned)__float_as_uint(v);
    atomicMax(&grid[r * NN + c], packed);
}

// ---------------- row max: one block per row --------------------------------
__global__ __launch_bounds__(256) void row_max_k(const unsigned long long* __restrict__ g,
                                                 float* __restrict__ out) {
    int r = blockIdx.x;
    float mx = SENTINEL;
    for (int c = threadIdx.x; c < NN; c += 256) {
        unsigned long long p = g[(size_t)r * NN + c];
        if (p) mx = fmaxf(mx, __uint_as_float((unsigned)p));
    }
    __shared__ float red[256];
    red[threadIdx.x] = mx;
    __syncthreads();
    for (int s = 128; s > 0; s >>= 1) {
        if (threadIdx.x < s) red[threadIdx.x] = fmaxf(red[threadIdx.x], red[threadIdx.x + s]);
        __syncthreads();
    }
    if (threadIdx.x == 0) out[r] = red[0];
}

// ---------------- col max: partials over row-chunks, then final -------------
#define CCHUNKS 25
#define CROWS   (KK / CCHUNKS)   // 40

__global__ __launch_bounds__(256) void col_partial(const unsigned long long* __restrict__ g,
                                                   float* __restrict__ part) {
    int n = blockIdx.x * 256 + threadIdx.x;
    if (n >= NN) return;
    int k0 = blockIdx.y * CROWS;
    float mx = SENTINEL;
    for (int k = k0; k < k0 + CROWS; ++k) {
        unsigned long long p = g[(size_t)k * NN + n];
        if (p) mx = fmaxf(mx, __uint_as_float((unsigned)p));
    }
    part[blockIdx.y * NN + n] = mx;
}

__global__ __launch_bounds__(256) void col_final(const float* __restrict__ part,
                                                 float* __restrict__ out) {
    int n = blockIdx.x * 256 + threadIdx.x;
    if (n >= NN) return;
    float mx = SENTINEL;
#pragma unroll
    for (int c = 0; c < CCHUNKS; ++c) mx = fmaxf(mx, part[c * NN + n]);
    out[KK + n] = mx;
}

extern "C" void kernel_launch(void* const* d_in, const int* in_sizes, int n_in,
                              void* d_out, int out_size, void* d_ws, size_t ws_size,
                              hipStream_t stream) {
    const float* in  = (const float*)d_in[0];
    // d_in[1] = T_out (zeros) — unused
    const int*   idx = (const int*)d_in[2];
    const float* w1  = (const float*)d_in[3];
    const float* b1  = (const float*)d_in[4];
    const float* w2  = (const float*)d_in[5];
    const float* b2  = (const float*)d_in[6];
    const float* w3  = (const float*)d_in[7];
    const float* b3  = (const float*)d_in[8];
    const float* w4  = (const float*)d_in[9];
    const float* b4  = (const float*)d_in[10];

    unsigned long long* grid = (unsigned long long*)d_ws;            // 8 MB
    float* part = (float*)((char*)d_ws + (size_t)KK * NN * 8);       // 100 KB
    float* out  = (float*)d_out;

    const int n2 = (KK * NN) / 2;  // ulonglong2 elements
    init_grid<<<(n2 + 255) / 256, 256, 0, stream>>>((ulonglong2*)grid, n2);

    mlp_scatter<<<(MM + 255) / 256, 256, 0, stream>>>(
        in, idx, w1, b1, w2, b2, w3, b3, w4, b4, grid);

    row_max_k<<<KK, 256, 0, stream>>>(grid, out);
    col_partial<<<dim3(4, CCHUNKS), 256, 0, stream>>>(grid, part);
    col_final<<<4, 256, 0, stream>>>(part, out);
}

// Round 3
// 171.920 us; speedup vs baseline: 1.0057x; 1.0048x over previous
//
#include <hip/hip_runtime.h>
#include <stdint.h>

#define KK 1000
#define NN 1000
#define MM 900000
#define FF 7
#define SENTINEL -9999.0f

// Compile-time unroller: every loop index reaches the body as a constant
// expression after inlining, so h1/h2 decompose into named scalars (SROA).
// Plain `#pragma unroll` left the arrays runtime-indexed at SROA time ->
// scratch spill (R1/R2: VGPR=32..40, +20MB HBM writes, VALUBusy 62%).
template <int N, typename F>
__device__ __forceinline__ void unroll_loop(F&& f) {
    if constexpr (N > 0) {
        unroll_loop<N - 1>(static_cast<F&&>(f));
        f(N - 1);
    }
}

// ---------------- init: zero the packed grid (ws is poisoned 0xAA) ----------
__global__ __launch_bounds__(256) void init_grid(ulonglong2* __restrict__ g, int n2) {
    int i = blockIdx.x * 256 + threadIdx.x;
    if (i < n2) g[i] = make_ulonglong2(0ULL, 0ULL);
}

// ---------------- MLP + last-write-wins scatter -----------------------------
__global__ __launch_bounds__(256, 4) void mlp_scatter(
    const float* __restrict__ in,    // [F][M]
    const int*   __restrict__ idx,   // [2][M]
    const float* __restrict__ w1, const float* __restrict__ b1,   // 18x7, 18
    const float* __restrict__ w2, const float* __restrict__ b2,   // 36x18, 36
    const float* __restrict__ w3, const float* __restrict__ b3,   // 36x36, 36
    const float* __restrict__ w4, const float* __restrict__ b4,   // 1x36, 1
    unsigned long long* __restrict__ grid)                        // K*N packed
{
    int m = blockIdx.x * 256 + threadIdx.x;
    if (m >= MM) return;

    float x[FF];
    unroll_loop<FF>([&](int f) { x[f] = in[f * MM + m]; });

    float h1[18];
    unroll_loop<18>([&](int o) {
        float a = b1[o];
        unroll_loop<FF>([&](int i) { a = fmaf(w1[o * FF + i], x[i], a); });
        h1[o] = fmaxf(a, 0.0f);
    });

    float h2[36];
    unroll_loop<36>([&](int o) {
        float a = b2[o];
        unroll_loop<18>([&](int i) { a = fmaf(w2[o * 18 + i], h1[i], a); });
        h2[o] = fmaxf(a, 0.0f);
    });

    // Layer 3 fused with layer 4: h3 never materializes (peak live set
    // ~= h2[36] + a few temps ~= 45 VGPRs, fits the 128-reg budget).
    float v = b4[0];
    unroll_loop<36>([&](int o) {
        float a = b3[o];
        unroll_loop<36>([&](int i) { a = fmaf(w3[o * 36 + i], h2[i], a); });
        v = fmaf(w4[o], fmaxf(a, 0.0f), v);
    });

    int r = idx[m];
    int c = idx[MM + m];
    // high word = m+1 (unique, later m wins => numpy last-write-wins),
    // low word = value bits (payload only, never decides the compare)
    unsigned long long packed =
        ((unsigned long long)(unsigned)(m + 1) << 32) | (unsigned)__float_as_uint(v);
    atomicMax(&grid[r * NN + c], packed);
}

// ---------------- row max: one block per row --------------------------------
__global__ __launch_bounds__(256) void row_max_k(const unsigned long long* __restrict__ g,
                                                 float* __restrict__ out) {
    int r = blockIdx.x;
    float mx = SENTINEL;
    for (int c = threadIdx.x; c < NN; c += 256) {
        unsigned long long p = g[(size_t)r * NN + c];
        if (p) mx = fmaxf(mx, __uint_as_float((unsigned)p));
    }
    __shared__ float red[256];
    red[threadIdx.x] = mx;
    __syncthreads();
    for (int s = 128; s > 0; s >>= 1) {
        if (threadIdx.x < s) red[threadIdx.x] = fmaxf(red[threadIdx.x], red[threadIdx.x + s]);
        __syncthreads();
    }
    if (threadIdx.x == 0) out[r] = red[0];
}

// ---------------- col max: partials over row-chunks, then final -------------
#define CCHUNKS 25
#define CROWS   (KK / CCHUNKS)   // 40

__global__ __launch_bounds__(256) void col_partial(const unsigned long long* __restrict__ g,
                                                   float* __restrict__ part) {
    int n = blockIdx.x * 256 + threadIdx.x;
    if (n >= NN) return;
    int k0 = blockIdx.y * CROWS;
    float mx = SENTINEL;
    for (int k = k0; k < k0 + CROWS; ++k) {
        unsigned long long p = g[(size_t)k * NN + n];
        if (p) mx = fmaxf(mx, __uint_as_float((unsigned)p));
    }
    part[blockIdx.y * NN + n] = mx;
}

__global__ __launch_bounds__(256) void col_final(const float* __restrict__ part,
                                                 float* __restrict__ out) {
    int n = blockIdx.x * 256 + threadIdx.x;
    if (n >= NN) return;
    float mx = SENTINEL;
#pragma unroll
    for (int c = 0; c < CCHUNKS; ++c) mx = fmaxf(mx, part[c * NN + n]);
    out[KK + n] = mx;
}

extern "C" void kernel_launch(void* const* d_in, const int* in_sizes, int n_in,
                              void* d_out, int out_size, void* d_ws, size_t ws_size,
                              hipStream_t stream) {
    const float* in  = (const float*)d_in[0];
    // d_in[1] = T_out (zeros) — unused
    const int*   idx = (const int*)d_in[2];
    const float* w1  = (const float*)d_in[3];
    const float* b1  = (const float*)d_in[4];
    const float* w2  = (const float*)d_in[5];
    const float* b2  = (const float*)d_in[6];
    const float* w3  = (const float*)d_in[7];
    const float* b3  = (const float*)d_in[8];
    const float* w4  = (const float*)d_in[9];
    const float* b4  = (const float*)d_in[10];

    unsigned long long* grid = (unsigned long long*)d_ws;            // 8 MB
    float* part = (float*)((char*)d_ws + (size_t)KK * NN * 8);       // 100 KB
    float* out  = (float*)d_out;

    const int n2 = (KK * NN) / 2;  // ulonglong2 elements
    init_grid<<<(n2 + 255) / 256, 256, 0, stream>>>((ulonglong2*)grid, n2);

    mlp_scatter<<<(MM + 255) / 256, 256, 0, stream>>>(
        in, idx, w1, b1, w2, b2, w3, b3, w4, b4, grid);

    row_max_k<<<KK, 256, 0, stream>>>(grid, out);
    col_partial<<<dim3(4, CCHUNKS), 256, 0, stream>>>(grid, part);
    col_final<<<4, 256, 0, stream>>>(part, out);
}